// Round 5
// baseline (607.222 us; speedup 1.0000x reference)
//
#include <hip/hip_runtime.h>
#include <hip/hip_bf16.h>
#include <stdint.h>
#include <limits.h>

#define N_NODES 50000
#define N_EDGES 500000
#define R_REL 8
#define HID 128
#define KDIM 1152            // R*HID + HID
#define N8 400000            // N_NODES * R_REL composite buckets
#define MT 32                // node tile per block in fused kernel
#define NBLK 1563            // ceil(N_NODES / MT)
#define CH 1160              // A-panel row stride in bf16 (2320 B, 16B-aligned)
#define EC 1024              // LDS edge cache capacity (tile avg ~320)
#define NUM_GRAPHS 64
#define NUM_CLASSES 16

typedef __attribute__((ext_vector_type(8))) short bf16x8;
typedef __attribute__((ext_vector_type(4))) float f32x4;

// ---------- helpers ----------
__device__ __forceinline__ uint16_t f2bf(float f) {
  uint32_t u = __float_as_uint(f);
  u += 0x7FFFu + ((u >> 16) & 1u);   // RNE
  return (uint16_t)(u >> 16);
}
__device__ __forceinline__ float bf2f(uint32_t b) {
  return __uint_as_float(b << 16);
}
__device__ __forceinline__ uint32_t pack2bf(float a, float b) {
  return (uint32_t)f2bf(a) | ((uint32_t)f2bf(b) << 16);
}

// ---------- merged prep: cvt | hist | bounds | prepw1 | prepw2 ----------
#define CVT_B 6250          // N_NODES*HID/4 / 256
#define HIST_B 1954
#define BND_B 196
#define PW_B 576            // HID*KDIM / 256
__global__ __launch_bounds__(256) void k_prep(const float* __restrict__ x, uint16_t* __restrict__ xb,
                                              const int* __restrict__ ei, const int* __restrict__ et,
                                              int* __restrict__ deg8,
                                              const int* __restrict__ batch,
                                              int* __restrict__ gs, int* __restrict__ ge,
                                              const float* __restrict__ W1, const float* __restrict__ root1,
                                              uint16_t* __restrict__ Wf1,
                                              const float* __restrict__ W2, const float* __restrict__ root2,
                                              uint16_t* __restrict__ Wf2) {
  int b = blockIdx.x;
  if (b < CVT_B) {                                  // x -> bf16
    int i = b * 256 + threadIdx.x;
    if (i * 4 < N_NODES * HID) {
      float4 v = *(const float4*)(x + (size_t)i * 4);
      uint16_t o[4] = {f2bf(v.x), f2bf(v.y), f2bf(v.z), f2bf(v.w)};
      *(uint2*)(xb + (size_t)i * 4) = *(uint2*)o;
    }
    return;
  }
  b -= CVT_B;
  if (b < HIST_B) {                                 // edge histogram
    int i = b * 256 + threadIdx.x;
    if (i < N_EDGES) atomicAdd(&deg8[ei[N_EDGES + i] * R_REL + et[i]], 1);
    return;
  }
  b -= HIST_B;
  if (b < BND_B) {                                  // graph boundaries (batch sorted)
    int i = b * 256 + threadIdx.x;
    if (i < N_NODES) {
      int g = batch[i];
      if (i == 0) gs[g] = 0;
      else { int pg = batch[i - 1]; if (pg != g) { ge[pg] = i; gs[g] = i; } }
      if (i == N_NODES - 1) ge[g] = N_NODES;
    }
    return;
  }
  b -= BND_B;
  {                                                 // prepw (layer 1 or 2)
    const float* W    = (b < PW_B) ? W1 : W2;
    const float* root = (b < PW_B) ? root1 : root2;
    uint16_t*    Wf   = (b < PW_B) ? Wf1 : Wf2;
    int idx = (b % PW_B) * 256 + threadIdx.x;
    // Wf idx = ((kcg*8+nt)*4+quad)*128 + l16*8 + e  <->  Wfull[k][n]
    int e = idx & 7, l16 = (idx >> 3) & 15, quad = (idx >> 7) & 3, nt = (idx >> 9) & 7, kcg = idx >> 12;
    int n = nt * 16 + l16;
    int k = kcg * 32 + quad * 8 + e;
    float v = (k < R_REL * HID) ? W[(size_t)k * HID + n] : root[(size_t)(k - R_REL * HID) * HID + n];
    Wf[idx] = f2bf(v);
  }
}

// ---------- scans ----------
__global__ __launch_bounds__(256) void k_scan1(const int* __restrict__ deg8, int* __restrict__ offs8,
                                               int* __restrict__ bsum) {
  __shared__ int sh[256];
  int t = threadIdx.x;
  int base = blockIdx.x * 1024 + t * 4;
  int v[4]; int s = 0;
  #pragma unroll
  for (int i = 0; i < 4; ++i) { int idx = base + i; v[i] = (idx < N8) ? deg8[idx] : 0; s += v[i]; }
  sh[t] = s;
  __syncthreads();
  for (int d = 1; d < 256; d <<= 1) {
    int add = (t >= d) ? sh[t - d] : 0;
    __syncthreads();
    sh[t] += add;
    __syncthreads();
  }
  int run = sh[t] - s;
  if (t == 255) bsum[blockIdx.x] = sh[255];
  #pragma unroll
  for (int i = 0; i < 4; ++i) { int idx = base + i; if (idx < N8) offs8[idx] = run; run += v[i]; }
}

__global__ __launch_bounds__(512) void k_scan2(int* __restrict__ bsum, int nb) {
  __shared__ int sh[512];
  int t = threadIdx.x;
  int v = (t < nb) ? bsum[t] : 0;
  sh[t] = v;
  __syncthreads();
  for (int d = 1; d < 512; d <<= 1) {
    int add = (t >= d) ? sh[t - d] : 0;
    __syncthreads();
    sh[t] += add;
    __syncthreads();
  }
  if (t < nb) bsum[t] = sh[t] - v;   // exclusive
}

__global__ __launch_bounds__(256) void k_scan3(int* __restrict__ offs8, int* __restrict__ nxt,
                                               const int* __restrict__ bsum) {
  int i = blockIdx.x * 256 + threadIdx.x;
  if (i < N8) {
    int o = offs8[i] + bsum[i >> 10];
    offs8[i] = o;
    nxt[i] = o;
  }
  if (i == 0) offs8[N8] = N_EDGES;
}

__global__ __launch_bounds__(256) void k_scatter(const int* __restrict__ ei, const int* __restrict__ et,
                                                 int* __restrict__ nxt, uint16_t* __restrict__ esrc) {
  int i = blockIdx.x * 256 + threadIdx.x;
  if (i < N_EDGES) {
    int key = ei[N_EDGES + i] * R_REL + et[i];
    int p = atomicAdd(&nxt[key], 1);
    esrc[p] = (uint16_t)ei[i];   // src < 2^16
  }
}

// ---------- fused aggregate + GEMM + bias + relu ----------
// 32-node tile. Full-width A-panel in LDS (no chunk barriers).
// Agg: wave w owns nodes [w*8, w*8+8) = 64 contiguous (node,rel) segments under the
// (dst,rel) sort -> flat segmented scan over the wave's contiguous edge range,
// 8 independent row-gathers in flight per group. Lane L covers features 2L..2L+1.
// Then one barrier and 36 K-chunks of MFMA.
template<bool OUT_BF16>
__global__ __launch_bounds__(256) void k_fused(const uint16_t* __restrict__ xb,
                                               const uint16_t* __restrict__ esrc,
                                               const int* __restrict__ offs8,
                                               const uint16_t* __restrict__ Wf,
                                               const float* __restrict__ bias,
                                               void* __restrict__ hout) {
  __shared__ uint16_t Abuf[MT][CH];      // 74240 B
  __shared__ uint16_t sedge[EC];         // 2048 B
  __shared__ int soffs[MT * R_REL + 1];  // 1028 B -> ~77.3 KB total -> 2 blocks/CU
  int t = threadIdx.x, w = t >> 6, L = t & 63;
  int quad = L >> 4, l16 = L & 15;
  int blockM = blockIdx.x * MT;
  int tileN = min(MT, N_NODES - blockM);
  int nSeg = tileN * R_REL;

  // stage offsets + edge list, zero the A-panel
  int ebase = offs8[blockM * R_REL];
  int ecnt  = offs8[blockM * R_REL + nSeg] - ebase;
  for (int i = t; i <= nSeg; i += 256) soffs[i] = offs8[blockM * R_REL + i] - ebase;
  bool cached = (ecnt <= EC);
  if (cached)
    for (int i = t; i < ecnt; i += 256) sedge[i] = esrc[ebase + i];
  {
    uint4 z = {0, 0, 0, 0};
    uint4* ap = (uint4*)&Abuf[0][0];
    #pragma unroll
    for (int i = 0; i < (MT * CH * 2) / 16 / 256 + 1; ++i) {
      int idx = i * 256 + t;
      if (idx < (MT * CH * 2) / 16) ap[idx] = z;
    }
  }
  __syncthreads();

  // ---- aggregation: flat segmented scan ----
  int segBase = w * 64;                  // wave's first tile-relative segment
  if (segBase < nSeg) {
    int segLim = min(segBase + 64, nSeg);
    int sBeg = soffs[segBase];
    int sEnd = soffs[segLim];
    int seg = segBase;
    int soffsNext = soffs[seg + 1];
    // skip leading empty segments (pre-zeroed)
    while (seg < segLim && soffsNext <= sBeg) {
      seg++;
      soffsNext = (seg < segLim) ? soffs[seg + 1] : INT_MAX;
    }
    float ax = 0.f, ay = 0.f;
    for (int g = sBeg; g < sEnd; g += 8) {
      int m8 = min(8, sEnd - g);
      float vx[8], vy[8];
      #pragma unroll
      for (int i = 0; i < 8; ++i) {
        if (i < m8) {
          int src = cached ? (int)sedge[g + i] : (int)esrc[ebase + g + i];
          uint32_t v = *(const uint32_t*)(xb + (size_t)src * HID + L * 2);
          vx[i] = bf2f(v & 0xFFFFu);
          vy[i] = bf2f(v >> 16);
        }
      }
      #pragma unroll
      for (int i = 0; i < 8; ++i) {
        if (i >= m8) break;
        ax += vx[i]; ay += vy[i];
        int e = g + i;
        while (e + 1 == soffsNext) {                  // segment(s) end here
          int c = soffsNext - soffs[seg];
          if (c > 0) {
            float inv = 1.f / (float)c;
            int m = seg >> 3, r = seg & 7;
            *(uint32_t*)&Abuf[m][r * HID + L * 2] = pack2bf(ax * inv, ay * inv);
          }
          ax = ay = 0.f;
          seg++;
          soffsNext = (seg < segLim) ? soffs[seg + 1] : INT_MAX;
        }
      }
    }
    // root chunk: node's own row -> K-slice [8*128, 9*128)
    #pragma unroll
    for (int nd = 0; nd < 8; ++nd) {
      int m = w * 8 + nd;
      int n = blockM + m;
      if (n < N_NODES) {
        uint32_t v = *(const uint32_t*)(xb + (size_t)n * HID + L * 2);
        *(uint32_t*)&Abuf[m][R_REL * HID + L * 2] = v;
      }
    }
  } else if (segBase < MT * R_REL) {
    // tail wave with no valid nodes: rows already zeroed
  }
  __syncthreads();

  // ---- MFMA phase: 36 K-chunks, no further barriers ----
  f32x4 acc[2][2];
  acc[0][0] = (f32x4){0,0,0,0}; acc[0][1] = (f32x4){0,0,0,0};
  acc[1][0] = (f32x4){0,0,0,0}; acc[1][1] = (f32x4){0,0,0,0};
  #pragma unroll 4
  for (int kcg = 0; kcg < KDIM / 32; ++kcg) {
    bf16x8 bfr[2];
    #pragma unroll
    for (int jt = 0; jt < 2; ++jt) {
      int nt = w * 2 + jt;
      bfr[jt] = *(const bf16x8*)(Wf + ((size_t)(kcg * 8 + nt) * 4) * 128 + L * 8);
    }
    bf16x8 af[2];
    #pragma unroll
    for (int it = 0; it < 2; ++it)
      af[it] = *(const bf16x8*)&Abuf[it * 16 + l16][kcg * 32 + quad * 8];
    #pragma unroll
    for (int it = 0; it < 2; ++it)
      #pragma unroll
      for (int jt = 0; jt < 2; ++jt)
        acc[it][jt] = __builtin_amdgcn_mfma_f32_16x16x32_bf16(af[it], bfr[jt], acc[it][jt], 0, 0, 0);
  }

  // epilogue: C/D layout col=lane&15, row=quad*4+reg
  #pragma unroll
  for (int it = 0; it < 2; ++it) {
    #pragma unroll
    for (int jt = 0; jt < 2; ++jt) {
      int c = (w * 2 + jt) * 16 + l16;
      float bb = bias[c];
      #pragma unroll
      for (int rg = 0; rg < 4; ++rg) {
        int row = blockM + it * 16 + quad * 4 + rg;
        if (row < N_NODES) {
          float o = fmaxf(acc[it][jt][rg] + bb, 0.f);
          if (OUT_BF16) ((uint16_t*)hout)[(size_t)row * HID + c] = f2bf(o);
          else          ((float*)hout)[(size_t)row * HID + c] = o;
        }
      }
    }
  }
}

// ---------- pooling: 4 partial blocks per graph + tiny final ----------
__global__ __launch_bounds__(256) void k_poolpart(const float* __restrict__ h,
                                                  const int* __restrict__ gs, const int* __restrict__ ge,
                                                  float* __restrict__ psum) {
  __shared__ float red[HID];
  int g = blockIdx.x >> 2, p = blockIdx.x & 3;
  int c = threadIdx.x & 127, ph = threadIdx.x >> 7;
  int s = gs[g], e = ge[g];
  int len = e - s;
  int quarter = (len + 3) >> 2;
  int n0 = s + p * quarter;
  int n1 = min(n0 + quarter, e);
  float acc = 0.f;
  for (int n = n0 + ph; n < n1; n += 2) acc += h[(size_t)n * HID + c];
  if (ph == 1) red[c] = acc;
  __syncthreads();
  if (ph == 0 && n0 < n1) atomicAdd(&psum[g * HID + c], acc + red[c]);
}

__global__ __launch_bounds__(1024) void k_final(const float* __restrict__ psum,
                                                const int* __restrict__ gs, const int* __restrict__ ge,
                                                const float* __restrict__ linW, const float* __restrict__ linb,
                                                float* __restrict__ out) {
  int i = threadIdx.x;              // 64*16 = 1024
  int g = i >> 4, c = i & 15;
  float inv = 1.f / fmaxf((float)(ge[g] - gs[g]), 1.f);
  float s = 0.f;
  #pragma unroll 8
  for (int k = 0; k < HID; ++k) s += psum[g * HID + k] * linW[k * NUM_CLASSES + c];
  out[i] = s * inv + linb[c];
}

// ---------- launch ----------
extern "C" void kernel_launch(void* const* d_in, const int* in_sizes, int n_in,
                              void* d_out, int out_size, void* d_ws, size_t ws_size,
                              hipStream_t stream) {
  const float* x     = (const float*)d_in[0];
  const int*   ei    = (const int*)d_in[1];   // [2,E]: [0..E) src, [E..2E) dst
  const int*   et    = (const int*)d_in[2];
  const int*   batch = (const int*)d_in[3];
  const float* W1    = (const float*)d_in[4];
  const float* root1 = (const float*)d_in[5];
  const float* b1    = (const float*)d_in[6];
  const float* W2    = (const float*)d_in[7];
  const float* root2 = (const float*)d_in[8];
  const float* b2    = (const float*)d_in[9];
  const float* linW  = (const float*)d_in[10];
  const float* linb  = (const float*)d_in[11];
  float* out = (float*)d_out;

  char* ws = (char*)d_ws;
  size_t off = 0;
  auto alloc = [&](size_t bytes) -> char* {
    char* p = ws + off;
    off += (bytes + 255) & ~(size_t)255;
    return p;
  };
  // zero-region: deg8 | gb | psum (contiguous, one memset)
  int*      deg8  = (int*)alloc((size_t)N8 * 4);                 // 1600000 (256-mult)
  int*      gb    = (int*)alloc(2 * NUM_GRAPHS * 4);             // 512
  float*    psum  = (float*)alloc((size_t)NUM_GRAPHS * HID * 4); // 32768
  size_t zbytes = (size_t)N8 * 4 + 512 + (size_t)NUM_GRAPHS * HID * 4;
  int*      gs    = gb;
  int*      ge    = gb + NUM_GRAPHS;
  int*      offs8 = (int*)alloc((size_t)(N8 + 1) * 4);
  int*      nxt   = (int*)alloc((size_t)N8 * 4);
  int*      bsum  = (int*)alloc(512 * 4);
  uint16_t* esrc  = (uint16_t*)alloc((size_t)N_EDGES * 2);
  uint16_t* xb    = (uint16_t*)alloc((size_t)N_NODES * HID * 2);
  uint16_t* Wf1   = (uint16_t*)alloc((size_t)HID * KDIM * 2);
  uint16_t* Wf2   = (uint16_t*)alloc((size_t)HID * KDIM * 2);
  uint16_t* h1b   = (uint16_t*)alloc((size_t)N_NODES * HID * 2);
  float*    h2    = (float*)alloc((size_t)N_NODES * HID * 4);

  hipMemsetAsync(deg8, 0, zbytes, stream);

  int nb = (N8 + 1023) / 1024;          // 391 <= 512
  k_prep<<<CVT_B + HIST_B + BND_B + 2 * PW_B, 256, 0, stream>>>(
      x, xb, ei, et, deg8, batch, gs, ge, W1, root1, Wf1, W2, root2, Wf2);
  k_scan1<<<nb, 256, 0, stream>>>(deg8, offs8, bsum);
  k_scan2<<<1, 512, 0, stream>>>(bsum, nb);
  k_scan3<<<(N8 + 255) / 256, 256, 0, stream>>>(offs8, nxt, bsum);
  k_scatter<<<(N_EDGES + 255) / 256, 256, 0, stream>>>(ei, et, nxt, esrc);

  k_fused<true ><<<NBLK, 256, 0, stream>>>(xb,  esrc, offs8, Wf1, b1, h1b);
  k_fused<false><<<NBLK, 256, 0, stream>>>(h1b, esrc, offs8, Wf2, b2, h2);

  k_poolpart<<<4 * NUM_GRAPHS, 256, 0, stream>>>(h2, gs, ge, psum);
  k_final<<<1, 1024, 0, stream>>>(psum, gs, ge, linW, linb, out);
}

// Round 6
// 383.837 us; speedup vs baseline: 1.5820x; 1.5820x over previous
//
#include <hip/hip_runtime.h>
#include <hip/hip_bf16.h>
#include <stdint.h>

#define N_NODES 50000
#define N_EDGES 500000
#define R_REL 8
#define HID 128
#define KDIM 1152            // R*HID + HID
#define N8 400000            // N_NODES * R_REL composite buckets
#define NPAD 50048           // 391 * 128
#define NUM_GRAPHS 64
#define NUM_CLASSES 16

typedef __attribute__((ext_vector_type(8))) short bf16x8;
typedef __attribute__((ext_vector_type(4))) float f32x4;

#define GLDS16(gp, lp) __builtin_amdgcn_global_load_lds( \
    (const __attribute__((address_space(1))) void*)(gp), \
    (__attribute__((address_space(3))) void*)(lp), 16, 0, 0)

// ---------- helpers ----------
__device__ __forceinline__ uint16_t f2bf(float f) {
  uint32_t u = __float_as_uint(f);
  u += 0x7FFFu + ((u >> 16) & 1u);   // RNE
  return (uint16_t)(u >> 16);
}
__device__ __forceinline__ float bf2f(uint32_t b) {
  return __uint_as_float(b << 16);
}
__device__ __forceinline__ uint32_t pack2bf(float a, float b) {
  return (uint32_t)f2bf(a) | ((uint32_t)f2bf(b) << 16);
}

// ---------- merged prep: cvt | hist | bounds | prepw1 | prepw2 ----------
#define CVT_B 6250          // N_NODES*HID/4 / 256
#define HIST_B 1954
#define BND_B 196
#define PW_B 576            // HID*KDIM / 256
__global__ __launch_bounds__(256) void k_prep(const float* __restrict__ x, uint16_t* __restrict__ xb,
                                              const int* __restrict__ ei, const int* __restrict__ et,
                                              int* __restrict__ deg8,
                                              const int* __restrict__ batch,
                                              int* __restrict__ gs, int* __restrict__ ge,
                                              const float* __restrict__ W1, const float* __restrict__ root1,
                                              uint16_t* __restrict__ Wf1,
                                              const float* __restrict__ W2, const float* __restrict__ root2,
                                              uint16_t* __restrict__ Wf2) {
  int b = blockIdx.x;
  if (b < CVT_B) {                                  // x -> bf16
    int i = b * 256 + threadIdx.x;
    if (i * 4 < N_NODES * HID) {
      float4 v = *(const float4*)(x + (size_t)i * 4);
      uint16_t o[4] = {f2bf(v.x), f2bf(v.y), f2bf(v.z), f2bf(v.w)};
      *(uint2*)(xb + (size_t)i * 4) = *(uint2*)o;
    }
    return;
  }
  b -= CVT_B;
  if (b < HIST_B) {                                 // edge histogram
    int i = b * 256 + threadIdx.x;
    if (i < N_EDGES) atomicAdd(&deg8[ei[N_EDGES + i] * R_REL + et[i]], 1);
    return;
  }
  b -= HIST_B;
  if (b < BND_B) {                                  // graph boundaries (batch sorted)
    int i = b * 256 + threadIdx.x;
    if (i < N_NODES) {
      int g = batch[i];
      if (i == 0) gs[g] = 0;
      else { int pg = batch[i - 1]; if (pg != g) { ge[pg] = i; gs[g] = i; } }
      if (i == N_NODES - 1) ge[g] = N_NODES;
    }
    return;
  }
  b -= BND_B;
  {                                                 // prepw: WbT[n][k] = bf16([W;root][k][n])
    const float* W    = (b < PW_B) ? W1 : W2;
    const float* root = (b < PW_B) ? root1 : root2;
    uint16_t*    Wf   = (b < PW_B) ? Wf1 : Wf2;
    int idx = (b % PW_B) * 256 + threadIdx.x;
    int n = idx / KDIM, k = idx % KDIM;
    float v = (k < R_REL * HID) ? W[(size_t)k * HID + n] : root[(size_t)(k - R_REL * HID) * HID + n];
    Wf[idx] = f2bf(v);
  }
}

// ---------- scans ----------
__global__ __launch_bounds__(256) void k_scan1(const int* __restrict__ deg8, int* __restrict__ offs8,
                                               int* __restrict__ bsum) {
  __shared__ int sh[256];
  int t = threadIdx.x;
  int base = blockIdx.x * 1024 + t * 4;
  int v[4]; int s = 0;
  #pragma unroll
  for (int i = 0; i < 4; ++i) { int idx = base + i; v[i] = (idx < N8) ? deg8[idx] : 0; s += v[i]; }
  sh[t] = s;
  __syncthreads();
  for (int d = 1; d < 256; d <<= 1) {
    int add = (t >= d) ? sh[t - d] : 0;
    __syncthreads();
    sh[t] += add;
    __syncthreads();
  }
  int run = sh[t] - s;
  if (t == 255) bsum[blockIdx.x] = sh[255];
  #pragma unroll
  for (int i = 0; i < 4; ++i) { int idx = base + i; if (idx < N8) offs8[idx] = run; run += v[i]; }
}

__global__ __launch_bounds__(512) void k_scan2(int* __restrict__ bsum, int nb) {
  __shared__ int sh[512];
  int t = threadIdx.x;
  int v = (t < nb) ? bsum[t] : 0;
  sh[t] = v;
  __syncthreads();
  for (int d = 1; d < 512; d <<= 1) {
    int add = (t >= d) ? sh[t - d] : 0;
    __syncthreads();
    sh[t] += add;
    __syncthreads();
  }
  if (t < nb) bsum[t] = sh[t] - v;   // exclusive
}

__global__ __launch_bounds__(256) void k_scan3(int* __restrict__ offs8, int* __restrict__ nxt,
                                               const int* __restrict__ bsum) {
  int i = blockIdx.x * 256 + threadIdx.x;
  if (i < N8) {
    int o = offs8[i] + bsum[i >> 10];
    offs8[i] = o;
    nxt[i] = o;
  }
  if (i == 0) offs8[N8] = N_EDGES;
}

__global__ __launch_bounds__(256) void k_scatter(const int* __restrict__ ei, const int* __restrict__ et,
                                                 int* __restrict__ nxt, uint16_t* __restrict__ esrc) {
  int i = blockIdx.x * 256 + threadIdx.x;
  if (i < N_EDGES) {
    int key = ei[N_EDGES + i] * R_REL + et[i];
    int p = atomicAdd(&nxt[key], 1);
    esrc[p] = (uint16_t)ei[i];   // src < 2^16
  }
}

// ---------- aggregation: one wave per node, register accumulators, no LDS ----------
// Under the (dst,rel) sort, node n's rel-r edges are segment [offs8[n*8+r], offs8[n*8+r+1]).
// Lane L owns features 2L, 2L+1. A[n] = [mean_r | x_n], bf16. Max occupancy -> TLP hides latency.
__global__ __launch_bounds__(256) void k_agg(const uint16_t* __restrict__ xb,
                                             const uint16_t* __restrict__ esrc,
                                             const int* __restrict__ offs8,
                                             uint16_t* __restrict__ A) {
  int n = (blockIdx.x * 256 + threadIdx.x) >> 6;
  int L = threadIdx.x & 63;
  if (n >= NPAD) return;
  uint32_t* Arow = (uint32_t*)(A + (size_t)n * KDIM);
  if (n >= N_NODES) {                     // GEMM tail padding rows
    #pragma unroll
    for (int r = 0; r <= R_REL; ++r) Arow[r * 64 + L] = 0u;
    return;
  }
  int o[R_REL + 1];
  #pragma unroll
  for (int r = 0; r <= R_REL; ++r) o[r] = offs8[n * R_REL + r];   // wave-uniform
  #pragma unroll 2
  for (int r = 0; r < R_REL; ++r) {
    int s = o[r], e = o[r + 1];
    float ax = 0.f, ay = 0.f;
    for (int j = s; j < e; ++j) {
      int src = (int)esrc[j];             // wave-uniform broadcast
      uint32_t v = *(const uint32_t*)(xb + (size_t)src * HID + L * 2);
      ax += bf2f(v & 0xFFFFu);
      ay += bf2f(v >> 16);
    }
    float inv = (e > s) ? 1.f / (float)(e - s) : 0.f;
    Arow[r * 64 + L] = pack2bf(ax * inv, ay * inv);
  }
  Arow[R_REL * 64 + L] = *(const uint32_t*)(xb + (size_t)n * HID + L * 2);   // root term
}

// ---------- h = relu(A @ WbT^T + b), bf16 MFMA 16x16x32, 128x128 tile (round-2 proven) ----------
template<bool OUT_BF16>
__global__ __launch_bounds__(256) void k_gemm(const uint16_t* __restrict__ A,
                                              const uint16_t* __restrict__ WbT,
                                              const float* __restrict__ bias,
                                              void* __restrict__ C) {
  __shared__ __align__(1024) uint16_t lds[2][128][32];   // [0]=A-tile [m][k], [1]=W-tile [n][k]; 16 KB
  int t = threadIdx.x;
  int w = t >> 6, L = t & 63;
  int quad = L >> 4, l16 = L & 15;
  int blockM = blockIdx.x * 128;

  f32x4 acc[2][8];
  #pragma unroll
  for (int i = 0; i < 2; ++i)
    #pragma unroll
    for (int j = 0; j < 8; ++j) acc[i][j] = (f32x4){0.f, 0.f, 0.f, 0.f};

  int srow = L >> 2;          // 0..15 within 16-row segment
  int selem = (L & 3) * 8;    // 8 bf16 = 16 B granule

  for (int k0 = 0; k0 < KDIM; k0 += 32) {
    #pragma unroll
    for (int q = 0; q < 2; ++q) {
      int seg = w * 2 + q;                       // 0..7 -> 16 rows each
      int m = seg * 16 + srow;
      const uint16_t* ga = A + (size_t)(blockM + m) * KDIM + k0 + selem;
      GLDS16(ga, &lds[0][seg * 16][0]);          // wave-uniform base; HW adds lane*16
      const uint16_t* gw = WbT + (size_t)m * KDIM + k0 + selem;
      GLDS16(gw, &lds[1][seg * 16][0]);
    }
    __syncthreads();
    bf16x8 af[2], bfr[8];
    #pragma unroll
    for (int i = 0; i < 2; ++i)
      af[i] = *(const bf16x8*)&lds[0][w * 32 + i * 16 + l16][quad * 8];
    #pragma unroll
    for (int j = 0; j < 8; ++j)
      bfr[j] = *(const bf16x8*)&lds[1][j * 16 + l16][quad * 8];
    #pragma unroll
    for (int i = 0; i < 2; ++i)
      #pragma unroll
      for (int j = 0; j < 8; ++j)
        acc[i][j] = __builtin_amdgcn_mfma_f32_16x16x32_bf16(af[i], bfr[j], acc[i][j], 0, 0, 0);
    __syncthreads();
  }
  // epilogue: C/D layout col=lane&15, row=quad*4+reg
  #pragma unroll
  for (int i = 0; i < 2; ++i) {
    int mrow = blockM + w * 32 + i * 16 + quad * 4;
    #pragma unroll
    for (int j = 0; j < 8; ++j) {
      int c = j * 16 + l16;
      float bb = bias[c];
      #pragma unroll
      for (int r = 0; r < 4; ++r) {
        int row = mrow + r;
        if (row < N_NODES) {
          float o = fmaxf(acc[i][j][r] + bb, 0.f);
          if (OUT_BF16) ((uint16_t*)C)[(size_t)row * HID + c] = f2bf(o);
          else          ((float*)C)[(size_t)row * HID + c] = o;
        }
      }
    }
  }
}

// ---------- pooling: 4 partial blocks per graph + tiny final ----------
__global__ __launch_bounds__(256) void k_poolpart(const float* __restrict__ h,
                                                  const int* __restrict__ gs, const int* __restrict__ ge,
                                                  float* __restrict__ psum) {
  __shared__ float red[HID];
  int g = blockIdx.x >> 2, p = blockIdx.x & 3;
  int c = threadIdx.x & 127, ph = threadIdx.x >> 7;
  int s = gs[g], e = ge[g];
  int len = e - s;
  int quarter = (len + 3) >> 2;
  int n0 = s + p * quarter;
  int n1 = min(n0 + quarter, e);
  float acc = 0.f;
  for (int n = n0 + ph; n < n1; n += 2) acc += h[(size_t)n * HID + c];
  if (ph == 1) red[c] = acc;
  __syncthreads();
  if (ph == 0 && n0 < n1) atomicAdd(&psum[g * HID + c], acc + red[c]);
}

__global__ __launch_bounds__(1024) void k_final(const float* __restrict__ psum,
                                                const int* __restrict__ gs, const int* __restrict__ ge,
                                                const float* __restrict__ linW, const float* __restrict__ linb,
                                                float* __restrict__ out) {
  int i = threadIdx.x;              // 64*16 = 1024
  int g = i >> 4, c = i & 15;
  float inv = 1.f / fmaxf((float)(ge[g] - gs[g]), 1.f);
  float s = 0.f;
  #pragma unroll 8
  for (int k = 0; k < HID; ++k) s += psum[g * HID + k] * linW[k * NUM_CLASSES + c];
  out[i] = s * inv + linb[c];
}

// ---------- launch ----------
extern "C" void kernel_launch(void* const* d_in, const int* in_sizes, int n_in,
                              void* d_out, int out_size, void* d_ws, size_t ws_size,
                              hipStream_t stream) {
  const float* x     = (const float*)d_in[0];
  const int*   ei    = (const int*)d_in[1];   // [2,E]: [0..E) src, [E..2E) dst
  const int*   et    = (const int*)d_in[2];
  const int*   batch = (const int*)d_in[3];
  const float* W1    = (const float*)d_in[4];
  const float* root1 = (const float*)d_in[5];
  const float* b1    = (const float*)d_in[6];
  const float* W2    = (const float*)d_in[7];
  const float* root2 = (const float*)d_in[8];
  const float* b2    = (const float*)d_in[9];
  const float* linW  = (const float*)d_in[10];
  const float* linb  = (const float*)d_in[11];
  float* out = (float*)d_out;

  char* ws = (char*)d_ws;
  size_t off = 0;
  auto alloc = [&](size_t bytes) -> char* {
    char* p = ws + off;
    off += (bytes + 255) & ~(size_t)255;
    return p;
  };
  // zero-region: deg8 | gb | psum (contiguous, one memset)
  int*      deg8  = (int*)alloc((size_t)N8 * 4);
  int*      gb    = (int*)alloc(2 * NUM_GRAPHS * 4);
  float*    psum  = (float*)alloc((size_t)NUM_GRAPHS * HID * 4);
  size_t zbytes = (size_t)N8 * 4 + 512 + (size_t)NUM_GRAPHS * HID * 4;
  int*      gs    = gb;
  int*      ge    = gb + NUM_GRAPHS;
  int*      offs8 = (int*)alloc((size_t)(N8 + 1) * 4);
  int*      nxt   = (int*)alloc((size_t)N8 * 4);
  int*      bsum  = (int*)alloc(512 * 4);
  uint16_t* esrc  = (uint16_t*)alloc((size_t)N_EDGES * 2);
  uint16_t* xb    = (uint16_t*)alloc((size_t)N_NODES * HID * 2);
  uint16_t* Wf1   = (uint16_t*)alloc((size_t)HID * KDIM * 2);
  uint16_t* Wf2   = (uint16_t*)alloc((size_t)HID * KDIM * 2);
  uint16_t* A     = (uint16_t*)alloc((size_t)NPAD * KDIM * 2);
  uint16_t* h1b   = (uint16_t*)alloc((size_t)N_NODES * HID * 2);
  float*    h2    = (float*)alloc((size_t)N_NODES * HID * 4);

  hipMemsetAsync(deg8, 0, zbytes, stream);

  int nb = (N8 + 1023) / 1024;          // 391 <= 512
  k_prep<<<CVT_B + HIST_B + BND_B + 2 * PW_B, 256, 0, stream>>>(
      x, xb, ei, et, deg8, batch, gs, ge, W1, root1, Wf1, W2, root2, Wf2);
  k_scan1<<<nb, 256, 0, stream>>>(deg8, offs8, bsum);
  k_scan2<<<1, 512, 0, stream>>>(bsum, nb);
  k_scan3<<<(N8 + 255) / 256, 256, 0, stream>>>(offs8, nxt, bsum);
  k_scatter<<<(N_EDGES + 255) / 256, 256, 0, stream>>>(ei, et, nxt, esrc);

  // layer 1
  k_agg<<<NPAD / 4, 256, 0, stream>>>(xb, esrc, offs8, A);
  k_gemm<true ><<<NPAD / 128, 256, 0, stream>>>(A, Wf1, b1, h1b);
  // layer 2
  k_agg<<<NPAD / 4, 256, 0, stream>>>(h1b, esrc, offs8, A);
  k_gemm<false><<<NPAD / 128, 256, 0, stream>>>(A, Wf2, b2, h2);

  k_poolpart<<<4 * NUM_GRAPHS, 256, 0, stream>>>(h2, gs, ge, psum);
  k_final<<<1, 1024, 0, stream>>>(psum, gs, ge, linW, linb, out);
}

// Round 7
// 370.481 us; speedup vs baseline: 1.6390x; 1.0361x over previous
//
#include <hip/hip_runtime.h>
#include <hip/hip_bf16.h>
#include <stdint.h>

#define N_NODES 50000
#define N_EDGES 500000
#define R_REL 8
#define HID 128
#define KIN 128              // GEMM K (input features)
#define KOUT 1152            // 9*128: slabs W_0..W_7 | root
#define N8 400000            // N_NODES * R_REL composite buckets
#define NPAD 50048           // 391 * 128
#define NUM_GRAPHS 64
#define NUM_CLASSES 16

typedef __attribute__((ext_vector_type(8))) short bf16x8;
typedef __attribute__((ext_vector_type(4))) float f32x4;

#define GLDS16(gp, lp) __builtin_amdgcn_global_load_lds( \
    (const __attribute__((address_space(1))) void*)(gp), \
    (__attribute__((address_space(3))) void*)(lp), 16, 0, 0)

// ---------- helpers ----------
__device__ __forceinline__ uint16_t f2bf(float f) {
  uint32_t u = __float_as_uint(f);
  u += 0x7FFFu + ((u >> 16) & 1u);   // RNE
  return (uint16_t)(u >> 16);
}
__device__ __forceinline__ float bf2f(uint32_t b) {
  return __uint_as_float(b << 16);
}
__device__ __forceinline__ uint32_t pack2bf(float a, float b) {
  return (uint32_t)f2bf(a) | ((uint32_t)f2bf(b) << 16);
}

// ---------- merged prep: cvt(+xb pad zero) | hist | bounds | h1b pad zero | prepw1 | prepw2 ----------
#define CVT_B 6256          // NPAD*HID/4 / 256
#define HIST_B 1954
#define BND_B 196
#define ZH_B 6              // (NPAD-N_NODES)*HID/4 / 256
#define PW_B 576            // KOUT*KIN / 256
__global__ __launch_bounds__(256) void k_prep(const float* __restrict__ x, uint16_t* __restrict__ xb,
                                              const int* __restrict__ ei, const int* __restrict__ et,
                                              int* __restrict__ deg8,
                                              const int* __restrict__ batch,
                                              int* __restrict__ gs, int* __restrict__ ge,
                                              uint16_t* __restrict__ h1b,
                                              const float* __restrict__ W1, const float* __restrict__ root1,
                                              uint16_t* __restrict__ Wf1,
                                              const float* __restrict__ W2, const float* __restrict__ root2,
                                              uint16_t* __restrict__ Wf2) {
  int b = blockIdx.x;
  if (b < CVT_B) {                                  // x -> bf16 (+ zero GEMM pad rows)
    int i = b * 256 + threadIdx.x;
    int i4 = i * 4;
    if (i4 < N_NODES * HID) {
      float4 v = *(const float4*)(x + (size_t)i4);
      uint16_t o[4] = {f2bf(v.x), f2bf(v.y), f2bf(v.z), f2bf(v.w)};
      *(uint2*)(xb + (size_t)i4) = *(uint2*)o;
    } else if (i4 < NPAD * HID) {
      uint2 z = {0u, 0u};
      *(uint2*)(xb + (size_t)i4) = z;
    }
    return;
  }
  b -= CVT_B;
  if (b < HIST_B) {                                 // edge histogram
    int i = b * 256 + threadIdx.x;
    if (i < N_EDGES) atomicAdd(&deg8[ei[N_EDGES + i] * R_REL + et[i]], 1);
    return;
  }
  b -= HIST_B;
  if (b < BND_B) {                                  // graph boundaries (batch sorted)
    int i = b * 256 + threadIdx.x;
    if (i < N_NODES) {
      int g = batch[i];
      if (i == 0) gs[g] = 0;
      else { int pg = batch[i - 1]; if (pg != g) { ge[pg] = i; gs[g] = i; } }
      if (i == N_NODES - 1) ge[g] = N_NODES;
    }
    return;
  }
  b -= BND_B;
  if (b < ZH_B) {                                   // zero h1b GEMM pad rows
    int idx = b * 256 + threadIdx.x;
    size_t pos = (size_t)N_NODES * HID + (size_t)idx * 4;
    if (pos < (size_t)NPAD * HID) {
      uint2 z = {0u, 0u};
      *(uint2*)(h1b + pos) = z;
    }
    return;
  }
  b -= ZH_B;
  {                                                 // prepw: Wf[kout][ki] = bf16(Wcat[ki][kout])
    const float* W    = (b < PW_B) ? W1 : W2;
    const float* root = (b < PW_B) ? root1 : root2;
    uint16_t*    Wf   = (b < PW_B) ? Wf1 : Wf2;
    int idx = (b % PW_B) * 256 + threadIdx.x;       // over KOUT*KIN
    int kout = idx >> 7, ki = idx & 127;
    int r = kout >> 7, no = kout & 127;
    float v = (r < R_REL) ? W[((size_t)r * 128 + ki) * 128 + no] : root[(size_t)ki * 128 + no];
    Wf[idx] = f2bf(v);
  }
}

// ---------- scans ----------
__global__ __launch_bounds__(256) void k_scan1(const int* __restrict__ deg8, int* __restrict__ offs8,
                                               int* __restrict__ bsum) {
  __shared__ int sh[256];
  int t = threadIdx.x;
  int base = blockIdx.x * 1024 + t * 4;
  int v[4]; int s = 0;
  #pragma unroll
  for (int i = 0; i < 4; ++i) { int idx = base + i; v[i] = (idx < N8) ? deg8[idx] : 0; s += v[i]; }
  sh[t] = s;
  __syncthreads();
  for (int d = 1; d < 256; d <<= 1) {
    int add = (t >= d) ? sh[t - d] : 0;
    __syncthreads();
    sh[t] += add;
    __syncthreads();
  }
  int run = sh[t] - s;
  if (t == 255) bsum[blockIdx.x] = sh[255];
  #pragma unroll
  for (int i = 0; i < 4; ++i) { int idx = base + i; if (idx < N8) offs8[idx] = run; run += v[i]; }
}

__global__ __launch_bounds__(512) void k_scan2(int* __restrict__ bsum, int nb) {
  __shared__ int sh[512];
  int t = threadIdx.x;
  int v = (t < nb) ? bsum[t] : 0;
  sh[t] = v;
  __syncthreads();
  for (int d = 1; d < 512; d <<= 1) {
    int add = (t >= d) ? sh[t - d] : 0;
    __syncthreads();
    sh[t] += add;
    __syncthreads();
  }
  if (t < nb) bsum[t] = sh[t] - v;   // exclusive
}

__global__ __launch_bounds__(256) void k_scan3(int* __restrict__ offs8, int* __restrict__ nxt,
                                               const int* __restrict__ bsum) {
  int i = blockIdx.x * 256 + threadIdx.x;
  if (i < N8) {
    int o = offs8[i] + bsum[i >> 10];
    offs8[i] = o;
    nxt[i] = o;
  }
  if (i == 0) offs8[N8] = N_EDGES;
}

__global__ __launch_bounds__(256) void k_scatter(const int* __restrict__ ei, const int* __restrict__ et,
                                                 int* __restrict__ nxt, uint16_t* __restrict__ esrc) {
  int i = blockIdx.x * 256 + threadIdx.x;
  if (i < N_EDGES) {
    int key = ei[N_EDGES + i] * R_REL + et[i];
    int p = atomicAdd(&nxt[key], 1);
    esrc[p] = (uint16_t)ei[i];   // src < 2^16
  }
}

// ---------- Y = A @ Wcat^T, bf16 MFMA, 128x128 tile, out cols = 9 slabs ----------
// grid (9, 391): x-fastest -> consecutive blocks share the A-tile (L2/L3 hot), W is 295 KB (L2-hot).
__global__ __launch_bounds__(256) void k_gemmY(const uint16_t* __restrict__ A,
                                               const uint16_t* __restrict__ WbT,
                                               uint16_t* __restrict__ Y) {
  __shared__ __align__(1024) uint16_t lds[2][128][32];   // [0]=A-tile [m][k], [1]=W-tile [n][k]
  int t = threadIdx.x;
  int w = t >> 6, L = t & 63;
  int quad = L >> 4, l16 = L & 15;
  int blockM = blockIdx.y * 128;
  int outB = blockIdx.x * 128;

  f32x4 acc[2][8];
  #pragma unroll
  for (int i = 0; i < 2; ++i)
    #pragma unroll
    for (int j = 0; j < 8; ++j) acc[i][j] = (f32x4){0.f, 0.f, 0.f, 0.f};

  int srow = L >> 2;
  int selem = (L & 3) * 8;

  for (int k0 = 0; k0 < KIN; k0 += 32) {
    #pragma unroll
    for (int q = 0; q < 2; ++q) {
      int seg = w * 2 + q;
      int m = seg * 16 + srow;
      GLDS16(A + (size_t)(blockM + m) * KIN + k0 + selem, &lds[0][seg * 16][0]);
      GLDS16(WbT + (size_t)(outB + m) * KIN + k0 + selem, &lds[1][seg * 16][0]);
    }
    __syncthreads();
    bf16x8 af[2], bfr[8];
    #pragma unroll
    for (int i = 0; i < 2; ++i)
      af[i] = *(const bf16x8*)&lds[0][w * 32 + i * 16 + l16][quad * 8];
    #pragma unroll
    for (int j = 0; j < 8; ++j)
      bfr[j] = *(const bf16x8*)&lds[1][j * 16 + l16][quad * 8];
    #pragma unroll
    for (int i = 0; i < 2; ++i)
      #pragma unroll
      for (int j = 0; j < 8; ++j)
        acc[i][j] = __builtin_amdgcn_mfma_f32_16x16x32_bf16(af[i], bfr[j], acc[i][j], 0, 0, 0);
    __syncthreads();
  }
  // epilogue: C/D layout col=lane&15, row=quad*4+reg; Y bf16
  #pragma unroll
  for (int i = 0; i < 2; ++i) {
    int mrow = blockM + w * 32 + i * 16 + quad * 4;
    #pragma unroll
    for (int j = 0; j < 8; ++j) {
      int c = outB + j * 16 + l16;
      #pragma unroll
      for (int r = 0; r < 4; ++r)
        Y[(size_t)(mrow + r) * KOUT + c] = f2bf(acc[i][j][r]);
    }
  }
}

// ---------- message pass: h = relu(Σ_r mean_r(Y_r[src]) + Y_root[n] + b) ----------
// One wave per node (k_agg's proven max-TLP structure), register accumulators, no LDS.
template<bool OUT_BF16>
__global__ __launch_bounds__(256) void k_msg(const uint16_t* __restrict__ Y,
                                             const uint16_t* __restrict__ esrc,
                                             const int* __restrict__ offs8,
                                             const float* __restrict__ bias,
                                             void* __restrict__ hout) {
  int n = (blockIdx.x * 256 + threadIdx.x) >> 6;
  n = __builtin_amdgcn_readfirstlane(n);
  int L = threadIdx.x & 63;
  if (n >= N_NODES) return;
  uint32_t rv = *(const uint32_t*)(Y + (size_t)n * KOUT + R_REL * HID + L * 2);   // root slab
  float ax = bf2f(rv & 0xFFFFu), ay = bf2f(rv >> 16);
  int o[R_REL + 1];
  #pragma unroll
  for (int r = 0; r <= R_REL; ++r) o[r] = offs8[n * R_REL + r];   // wave-uniform
  #pragma unroll 2
  for (int r = 0; r < R_REL; ++r) {
    int s = o[r], e = o[r + 1];
    float sx = 0.f, sy = 0.f;
    for (int j = s; j < e; ++j) {
      int src = (int)esrc[j];             // wave-uniform broadcast
      uint32_t v = *(const uint32_t*)(Y + (size_t)src * KOUT + r * HID + L * 2);
      sx += bf2f(v & 0xFFFFu);
      sy += bf2f(v >> 16);
    }
    float inv = (e > s) ? 1.f / (float)(e - s) : 0.f;
    ax += sx * inv;
    ay += sy * inv;
  }
  float2 bb = *(const float2*)(bias + L * 2);
  ax = fmaxf(ax + bb.x, 0.f);
  ay = fmaxf(ay + bb.y, 0.f);
  if (OUT_BF16)
    *(uint32_t*)((uint16_t*)hout + (size_t)n * HID + L * 2) = pack2bf(ax, ay);
  else {
    float2 o2 = {ax, ay};
    *(float2*)((float*)hout + (size_t)n * HID + L * 2) = o2;
  }
}

// ---------- pooling: 4 partial blocks per graph + tiny final ----------
__global__ __launch_bounds__(256) void k_poolpart(const float* __restrict__ h,
                                                  const int* __restrict__ gs, const int* __restrict__ ge,
                                                  float* __restrict__ psum) {
  __shared__ float red[HID];
  int g = blockIdx.x >> 2, p = blockIdx.x & 3;
  int c = threadIdx.x & 127, ph = threadIdx.x >> 7;
  int s = gs[g], e = ge[g];
  int len = e - s;
  int quarter = (len + 3) >> 2;
  int n0 = s + p * quarter;
  int n1 = min(n0 + quarter, e);
  float acc = 0.f;
  for (int n = n0 + ph; n < n1; n += 2) acc += h[(size_t)n * HID + c];
  if (ph == 1) red[c] = acc;
  __syncthreads();
  if (ph == 0 && n0 < n1) atomicAdd(&psum[g * HID + c], acc + red[c]);
}

__global__ __launch_bounds__(1024) void k_final(const float* __restrict__ psum,
                                                const int* __restrict__ gs, const int* __restrict__ ge,
                                                const float* __restrict__ linW, const float* __restrict__ linb,
                                                float* __restrict__ out) {
  int i = threadIdx.x;              // 64*16 = 1024
  int g = i >> 4, c = i & 15;
  float inv = 1.f / fmaxf((float)(ge[g] - gs[g]), 1.f);
  float s = 0.f;
  #pragma unroll 8
  for (int k = 0; k < HID; ++k) s += psum[g * HID + k] * linW[k * NUM_CLASSES + c];
  out[i] = s * inv + linb[c];
}

// ---------- launch ----------
extern "C" void kernel_launch(void* const* d_in, const int* in_sizes, int n_in,
                              void* d_out, int out_size, void* d_ws, size_t ws_size,
                              hipStream_t stream) {
  const float* x     = (const float*)d_in[0];
  const int*   ei    = (const int*)d_in[1];   // [2,E]: [0..E) src, [E..2E) dst
  const int*   et    = (const int*)d_in[2];
  const int*   batch = (const int*)d_in[3];
  const float* W1    = (const float*)d_in[4];
  const float* root1 = (const float*)d_in[5];
  const float* b1    = (const float*)d_in[6];
  const float* W2    = (const float*)d_in[7];
  const float* root2 = (const float*)d_in[8];
  const float* b2    = (const float*)d_in[9];
  const float* linW  = (const float*)d_in[10];
  const float* linb  = (const float*)d_in[11];
  float* out = (float*)d_out;

  char* ws = (char*)d_ws;
  size_t off = 0;
  auto alloc = [&](size_t bytes) -> char* {
    char* p = ws + off;
    off += (bytes + 255) & ~(size_t)255;
    return p;
  };
  // zero-region: deg8 | gb | psum (contiguous, one memset)
  int*      deg8  = (int*)alloc((size_t)N8 * 4);
  int*      gb    = (int*)alloc(2 * NUM_GRAPHS * 4);
  float*    psum  = (float*)alloc((size_t)NUM_GRAPHS * HID * 4);
  size_t zbytes = (size_t)N8 * 4 + 512 + (size_t)NUM_GRAPHS * HID * 4;
  int*      gs    = gb;
  int*      ge    = gb + NUM_GRAPHS;
  int*      offs8 = (int*)alloc((size_t)(N8 + 1) * 4);
  int*      nxt   = (int*)alloc((size_t)N8 * 4);
  int*      bsum  = (int*)alloc(512 * 4);
  uint16_t* esrc  = (uint16_t*)alloc((size_t)N_EDGES * 2);
  uint16_t* xb    = (uint16_t*)alloc((size_t)NPAD * HID * 2);
  uint16_t* Wf1   = (uint16_t*)alloc((size_t)KOUT * KIN * 2);
  uint16_t* Wf2   = (uint16_t*)alloc((size_t)KOUT * KIN * 2);
  uint16_t* Y     = (uint16_t*)alloc((size_t)NPAD * KOUT * 2);   // 115 MB, reused both layers
  uint16_t* h1b   = (uint16_t*)alloc((size_t)NPAD * HID * 2);
  float*    h2    = (float*)alloc((size_t)N_NODES * HID * 4);

  hipMemsetAsync(deg8, 0, zbytes, stream);

  int nb = (N8 + 1023) / 1024;          // 391 <= 512
  k_prep<<<CVT_B + HIST_B + BND_B + ZH_B + 2 * PW_B, 256, 0, stream>>>(
      x, xb, ei, et, deg8, batch, gs, ge, h1b, W1, root1, Wf1, W2, root2, Wf2);
  k_scan1<<<nb, 256, 0, stream>>>(deg8, offs8, bsum);
  k_scan2<<<1, 512, 0, stream>>>(bsum, nb);
  k_scan3<<<(N8 + 255) / 256, 256, 0, stream>>>(offs8, nxt, bsum);
  k_scatter<<<(N_EDGES + 255) / 256, 256, 0, stream>>>(ei, et, nxt, esrc);

  // layer 1
  k_gemmY<<<dim3(KOUT / 128, NPAD / 128), 256, 0, stream>>>(xb, Wf1, Y);
  k_msg<true ><<<N_NODES / 4, 256, 0, stream>>>(Y, esrc, offs8, b1, h1b);
  // layer 2
  k_gemmY<<<dim3(KOUT / 128, NPAD / 128), 256, 0, stream>>>(h1b, Wf2, Y);
  k_msg<false><<<N_NODES / 4, 256, 0, stream>>>(Y, esrc, offs8, b2, h2);

  k_poolpart<<<4 * NUM_GRAPHS, 256, 0, stream>>>(h2, gs, ge, psum);
  k_final<<<1, 1024, 0, stream>>>(psum, gs, ge, linW, linb, out);
}

// Round 8
// 316.237 us; speedup vs baseline: 1.9202x; 1.1715x over previous
//
#include <hip/hip_runtime.h>
#include <hip/hip_bf16.h>
#include <stdint.h>

#define N_NODES 50000
#define N_EDGES 500000
#define R_REL 8
#define HID 128
#define KIN 128              // GEMM K (input features)
#define KOUT 1152            // 9*128: slabs W_0..W_7 | root
#define N8 400000            // N_NODES * R_REL composite buckets
#define NPAD 50048           // 782 * 64
#define NUM_GRAPHS 64
#define NUM_CLASSES 16

typedef __attribute__((ext_vector_type(8))) short bf16x8;
typedef __attribute__((ext_vector_type(4))) float f32x4;

// ---------- helpers ----------
__device__ __forceinline__ uint16_t f2bf(float f) {
  uint32_t u = __float_as_uint(f);
  u += 0x7FFFu + ((u >> 16) & 1u);   // RNE
  return (uint16_t)(u >> 16);
}
__device__ __forceinline__ float bf2f(uint32_t b) {
  return __uint_as_float(b << 16);
}
__device__ __forceinline__ uint32_t pack2bf(float a, float b) {
  return (uint32_t)f2bf(a) | ((uint32_t)f2bf(b) << 16);
}

// ---------- merged prep: hist | bounds | prepw1 | prepw2 ----------
#define HIST_B 1954
#define BND_B 196
#define PW_B 576            // KOUT*KIN / 256
__global__ __launch_bounds__(256) void k_prep(const int* __restrict__ ei, const int* __restrict__ et,
                                              int* __restrict__ deg8,
                                              const int* __restrict__ batch,
                                              int* __restrict__ gs, int* __restrict__ ge,
                                              const float* __restrict__ W1, const float* __restrict__ root1,
                                              uint16_t* __restrict__ Wf1,
                                              const float* __restrict__ W2, const float* __restrict__ root2,
                                              uint16_t* __restrict__ Wf2) {
  int b = blockIdx.x;
  if (b < HIST_B) {                                 // edge histogram
    int i = b * 256 + threadIdx.x;
    if (i < N_EDGES) atomicAdd(&deg8[ei[N_EDGES + i] * R_REL + et[i]], 1);
    return;
  }
  b -= HIST_B;
  if (b < BND_B) {                                  // graph boundaries (batch sorted)
    int i = b * 256 + threadIdx.x;
    if (i < N_NODES) {
      int g = batch[i];
      if (i == 0) gs[g] = 0;
      else { int pg = batch[i - 1]; if (pg != g) { ge[pg] = i; gs[g] = i; } }
      if (i == N_NODES - 1) ge[g] = N_NODES;
    }
    return;
  }
  b -= BND_B;
  {
    // prepw: Wf in B-frag order. frag f=(s*8+nt)*4+kc holds 64 lanes x 16B,
    // lane L=(quad,l16): element Wcat[k = kc*32+quad*8+e][col = s*128+nt*16+l16]
    const float* W    = (b < PW_B) ? W1 : W2;
    const float* root = (b < PW_B) ? root1 : root2;
    uint16_t*    Wf   = (b < PW_B) ? Wf1 : Wf2;
    int idx = (b % PW_B) * 256 + threadIdx.x;       // over KOUT*KIN
    int e = idx & 7, L = (idx >> 3) & 63, f = idx >> 9;
    int quad = L >> 4, l16 = L & 15;
    int kc = f & 3, nt = (f >> 2) & 7, s = f >> 5;
    int k = kc * 32 + quad * 8 + e;
    int no = nt * 16 + l16;
    float v = (s < R_REL) ? W[((size_t)s * KIN + k) * HID + no] : root[(size_t)k * HID + no];
    Wf[idx] = f2bf(v);
  }
}

// ---------- scans ----------
__global__ __launch_bounds__(256) void k_scan1(const int* __restrict__ deg8, int* __restrict__ offs8,
                                               int* __restrict__ bsum) {
  __shared__ int sh[256];
  int t = threadIdx.x;
  int base = blockIdx.x * 1024 + t * 4;
  int v[4]; int s = 0;
  #pragma unroll
  for (int i = 0; i < 4; ++i) { int idx = base + i; v[i] = (idx < N8) ? deg8[idx] : 0; s += v[i]; }
  sh[t] = s;
  __syncthreads();
  for (int d = 1; d < 256; d <<= 1) {
    int add = (t >= d) ? sh[t - d] : 0;
    __syncthreads();
    sh[t] += add;
    __syncthreads();
  }
  int run = sh[t] - s;
  if (t == 255) bsum[blockIdx.x] = sh[255];
  #pragma unroll
  for (int i = 0; i < 4; ++i) { int idx = base + i; if (idx < N8) offs8[idx] = run; run += v[i]; }
}

__global__ __launch_bounds__(512) void k_scan2(int* __restrict__ bsum, int nb) {
  __shared__ int sh[512];
  int t = threadIdx.x;
  int v = (t < nb) ? bsum[t] : 0;
  sh[t] = v;
  __syncthreads();
  for (int d = 1; d < 512; d <<= 1) {
    int add = (t >= d) ? sh[t - d] : 0;
    __syncthreads();
    sh[t] += add;
    __syncthreads();
  }
  if (t < nb) bsum[t] = sh[t] - v;   // exclusive
}

__global__ __launch_bounds__(256) void k_scan3(int* __restrict__ offs8, int* __restrict__ nxt,
                                               const int* __restrict__ bsum) {
  int i = blockIdx.x * 256 + threadIdx.x;
  if (i < N8) {
    int o = offs8[i] + bsum[i >> 10];
    offs8[i] = o;
    nxt[i] = o;
  }
  if (i == 0) offs8[N8] = N_EDGES;
}

// scatter: place edge; also emit per-edge packed (src|rel<<16) and weight 1/cnt
__global__ __launch_bounds__(256) void k_scatter(const int* __restrict__ ei, const int* __restrict__ et,
                                                 const int* __restrict__ deg8, int* __restrict__ nxt,
                                                 uint32_t* __restrict__ epack, float* __restrict__ wgt) {
  int i = blockIdx.x * 256 + threadIdx.x;
  if (i < N_EDGES) {
    int rel = et[i];
    int key = ei[N_EDGES + i] * R_REL + rel;
    int p = atomicAdd(&nxt[key], 1);
    epack[p] = (uint32_t)ei[i] | ((uint32_t)rel << 16);   // src < 2^16
    wgt[p] = 1.0f / (float)deg8[key];                     // mean weight (cnt >= 1)
  }
}

// ---------- Y = in @ Wcat^T, register-resident bf16 MFMA (no LDS, no barriers) ----------
// 1 wave per block, 64 rows. A-slice (64x128) held in VGPRs, loaded once.
// B-frags streamed directly from Wf (frag order, L2-hot). 9 slabs x 4 kc x 32 MFMA.
template<bool IN_BF16>
__global__ __launch_bounds__(64) void k_gemmY(const void* __restrict__ in,
                                              const uint16_t* __restrict__ Wf,
                                              uint16_t* __restrict__ Y) {
  int L = threadIdx.x;
  int quad = L >> 4, l16 = L & 15;
  int blockM = blockIdx.x * 64;

  bf16x8 af[4][4];            // [row-group][kchunk], A[m=l16][k=quad*8+e]
  #pragma unroll
  for (int i = 0; i < 4; ++i) {
    int row = blockM + i * 16 + l16;
    bool valid = row < N_NODES;
    #pragma unroll
    for (int kc = 0; kc < 4; ++kc) {
      if (IN_BF16) {
        uint4 v = {0u, 0u, 0u, 0u};
        if (valid) v = *(const uint4*)((const uint16_t*)in + (size_t)row * KIN + kc * 32 + quad * 8);
        union { uint4 u; bf16x8 b; } cv; cv.u = v;
        af[i][kc] = cv.b;
      } else {
        float4 a = {0.f,0.f,0.f,0.f}, c = {0.f,0.f,0.f,0.f};
        if (valid) {
          const float* p = (const float*)in + (size_t)row * KIN + kc * 32 + quad * 8;
          a = *(const float4*)p;
          c = *(const float4*)(p + 4);
        }
        bf16x8 r;
        r[0] = (short)f2bf(a.x); r[1] = (short)f2bf(a.y); r[2] = (short)f2bf(a.z); r[3] = (short)f2bf(a.w);
        r[4] = (short)f2bf(c.x); r[5] = (short)f2bf(c.y); r[6] = (short)f2bf(c.z); r[7] = (short)f2bf(c.w);
        af[i][kc] = r;
      }
    }
  }

  #pragma unroll 1
  for (int s = 0; s < 9; ++s) {
    f32x4 acc[4][8];
    #pragma unroll
    for (int i = 0; i < 4; ++i)
      #pragma unroll
      for (int nt = 0; nt < 8; ++nt) acc[i][nt] = (f32x4){0.f, 0.f, 0.f, 0.f};
    #pragma unroll
    for (int kc = 0; kc < 4; ++kc) {
      bf16x8 bfr[8];
      #pragma unroll
      for (int nt = 0; nt < 8; ++nt) {
        int f = (s * 8 + nt) * 4 + kc;
        bfr[nt] = *(const bf16x8*)(Wf + (size_t)f * 512 + L * 8);   // 16B/lane coalesced
      }
      #pragma unroll
      for (int i = 0; i < 4; ++i)
        #pragma unroll
        for (int nt = 0; nt < 8; ++nt)
          acc[i][nt] = __builtin_amdgcn_mfma_f32_16x16x32_bf16(af[i][kc], bfr[nt], acc[i][nt], 0, 0, 0);
    }
    // epilogue slab s: C/D layout col=lane&15, row=quad*4+reg
    #pragma unroll
    for (int i = 0; i < 4; ++i) {
      #pragma unroll
      for (int nt = 0; nt < 8; ++nt) {
        int col = s * 128 + nt * 16 + l16;
        #pragma unroll
        for (int rg = 0; rg < 4; ++rg) {
          int row = blockM + i * 16 + quad * 4 + rg;
          Y[(size_t)row * KOUT + col] = f2bf(acc[i][nt][rg]);
        }
      }
    }
  }
}

// ---------- message pass: h = relu(Σ_e w_e * Y_rel[src] + Y_root[n] + b) ----------
// One wave per node; FLAT edge loop with 8 independent gathers in flight; no segment logic.
template<bool OUT_BF16>
__global__ __launch_bounds__(256) void k_msg(const uint16_t* __restrict__ Y,
                                             const uint32_t* __restrict__ epack,
                                             const float* __restrict__ wgt,
                                             const int* __restrict__ offs8,
                                             const float* __restrict__ bias,
                                             void* __restrict__ hout) {
  int n = (blockIdx.x * 256 + threadIdx.x) >> 6;
  n = __builtin_amdgcn_readfirstlane(n);
  int L = threadIdx.x & 63;
  if (n >= N_NODES) return;
  uint32_t rv = *(const uint32_t*)(Y + (size_t)n * KOUT + R_REL * HID + L * 2);   // root slab
  float ax = bf2f(rv & 0xFFFFu), ay = bf2f(rv >> 16);
  int o0 = offs8[n * R_REL];
  int o8 = offs8[n * R_REL + R_REL];
  for (int g = o0; g < o8; g += 8) {
    int m8 = min(8, o8 - g);
    uint32_t pv[8]; float wv[8]; uint32_t vv[8];
    #pragma unroll
    for (int i = 0; i < 8; ++i) if (i < m8) { pv[i] = epack[g + i]; wv[i] = wgt[g + i]; }
    #pragma unroll
    for (int i = 0; i < 8; ++i) if (i < m8)
      vv[i] = *(const uint32_t*)(Y + (size_t)(pv[i] & 0xFFFFu) * KOUT + (pv[i] >> 16) * HID + L * 2);
    #pragma unroll
    for (int i = 0; i < 8; ++i) if (i < m8) {
      ax += bf2f(vv[i] & 0xFFFFu) * wv[i];
      ay += bf2f(vv[i] >> 16) * wv[i];
    }
  }
  float2 bb = *(const float2*)(bias + L * 2);
  ax = fmaxf(ax + bb.x, 0.f);
  ay = fmaxf(ay + bb.y, 0.f);
  if (OUT_BF16)
    *(uint32_t*)((uint16_t*)hout + (size_t)n * HID + L * 2) = pack2bf(ax, ay);
  else {
    float2 o2 = {ax, ay};
    *(float2*)((float*)hout + (size_t)n * HID + L * 2) = o2;
  }
}

// ---------- pooling: 4 partial blocks per graph + tiny final ----------
__global__ __launch_bounds__(256) void k_poolpart(const float* __restrict__ h,
                                                  const int* __restrict__ gs, const int* __restrict__ ge,
                                                  float* __restrict__ psum) {
  __shared__ float red[HID];
  int g = blockIdx.x >> 2, p = blockIdx.x & 3;
  int c = threadIdx.x & 127, ph = threadIdx.x >> 7;
  int s = gs[g], e = ge[g];
  int len = e - s;
  int quarter = (len + 3) >> 2;
  int n0 = s + p * quarter;
  int n1 = min(n0 + quarter, e);
  float acc = 0.f;
  for (int n = n0 + ph; n < n1; n += 2) acc += h[(size_t)n * HID + c];
  if (ph == 1) red[c] = acc;
  __syncthreads();
  if (ph == 0 && n0 < n1) atomicAdd(&psum[g * HID + c], acc + red[c]);
}

__global__ __launch_bounds__(1024) void k_final(const float* __restrict__ psum,
                                                const int* __restrict__ gs, const int* __restrict__ ge,
                                                const float* __restrict__ linW, const float* __restrict__ linb,
                                                float* __restrict__ out) {
  int i = threadIdx.x;              // 64*16 = 1024
  int g = i >> 4, c = i & 15;
  float inv = 1.f / fmaxf((float)(ge[g] - gs[g]), 1.f);
  float s = 0.f;
  #pragma unroll 8
  for (int k = 0; k < HID; ++k) s += psum[g * HID + k] * linW[k * NUM_CLASSES + c];
  out[i] = s * inv + linb[c];
}

// ---------- launch ----------
extern "C" void kernel_launch(void* const* d_in, const int* in_sizes, int n_in,
                              void* d_out, int out_size, void* d_ws, size_t ws_size,
                              hipStream_t stream) {
  const float* x     = (const float*)d_in[0];
  const int*   ei    = (const int*)d_in[1];   // [2,E]: [0..E) src, [E..2E) dst
  const int*   et    = (const int*)d_in[2];
  const int*   batch = (const int*)d_in[3];
  const float* W1    = (const float*)d_in[4];
  const float* root1 = (const float*)d_in[5];
  const float* b1    = (const float*)d_in[6];
  const float* W2    = (const float*)d_in[7];
  const float* root2 = (const float*)d_in[8];
  const float* b2    = (const float*)d_in[9];
  const float* linW  = (const float*)d_in[10];
  const float* linb  = (const float*)d_in[11];
  float* out = (float*)d_out;

  char* ws = (char*)d_ws;
  size_t off = 0;
  auto alloc = [&](size_t bytes) -> char* {
    char* p = ws + off;
    off += (bytes + 255) & ~(size_t)255;
    return p;
  };
  // zero-region: deg8 | gb | psum (contiguous, one memset)
  int*      deg8  = (int*)alloc((size_t)N8 * 4);
  int*      gb    = (int*)alloc(2 * NUM_GRAPHS * 4);
  float*    psum  = (float*)alloc((size_t)NUM_GRAPHS * HID * 4);
  size_t zbytes = (size_t)N8 * 4 + 512 + (size_t)NUM_GRAPHS * HID * 4;
  int*      gs    = gb;
  int*      ge    = gb + NUM_GRAPHS;
  int*      offs8 = (int*)alloc((size_t)(N8 + 1) * 4);
  int*      nxt   = (int*)alloc((size_t)N8 * 4);
  int*      bsum  = (int*)alloc(512 * 4);
  uint32_t* epack = (uint32_t*)alloc((size_t)N_EDGES * 4);
  float*    wgt   = (float*)alloc((size_t)N_EDGES * 4);
  uint16_t* Wf1   = (uint16_t*)alloc((size_t)KOUT * KIN * 2);
  uint16_t* Wf2   = (uint16_t*)alloc((size_t)KOUT * KIN * 2);
  uint16_t* Y     = (uint16_t*)alloc((size_t)NPAD * KOUT * 2);   // 115 MB, reused both layers
  uint16_t* h1b   = (uint16_t*)alloc((size_t)N_NODES * HID * 2);
  float*    h2    = (float*)alloc((size_t)N_NODES * HID * 4);

  hipMemsetAsync(deg8, 0, zbytes, stream);

  int nb = (N8 + 1023) / 1024;          // 391 <= 512
  k_prep<<<HIST_B + BND_B + 2 * PW_B, 256, 0, stream>>>(
      ei, et, deg8, batch, gs, ge, W1, root1, Wf1, W2, root2, Wf2);
  k_scan1<<<nb, 256, 0, stream>>>(deg8, offs8, bsum);
  k_scan2<<<1, 512, 0, stream>>>(bsum, nb);
  k_scan3<<<(N8 + 255) / 256, 256, 0, stream>>>(offs8, nxt, bsum);
  k_scatter<<<(N_EDGES + 255) / 256, 256, 0, stream>>>(ei, et, deg8, nxt, epack, wgt);

  // layer 1
  k_gemmY<false><<<NPAD / 64, 64, 0, stream>>>(x, Wf1, Y);
  k_msg<true ><<<N_NODES / 4, 256, 0, stream>>>(Y, epack, wgt, offs8, b1, h1b);
  // layer 2
  k_gemmY<true ><<<NPAD / 64, 64, 0, stream>>>(h1b, Wf2, Y);
  k_msg<false><<<N_NODES / 4, 256, 0, stream>>>(Y, epack, wgt, offs8, b2, h2);

  k_poolpart<<<4 * NUM_GRAPHS, 256, 0, stream>>>(h2, gs, ge, psum);
  k_final<<<1, 1024, 0, stream>>>(psum, gs, ge, linW, linb, out);
}